// Round 3
// baseline (232.810 us; speedup 1.0000x reference)
//
#include <hip/hip_runtime.h>
#include <hip/hip_bf16.h>

// GraphNodeEdgeConvolution: N=2048, K=8, FN=16, O=32
// fp32 in / fp32 out. Inputs bound BY SIZE.
// R8: fuse reduce_k + epilogue_k into tail_k (block owns 64 j-columns:
// finish plane reduction in LDS, emit out[j,:] directly). Saves one
// launch + the aggT HBM round trip. main_k unchanged (R7 proved it
// BW-bound: occupancy 2->4 blocks/CU was neutral).
// Accounting: timed region carries ~157us of harness 512MiB poison
// fills (2x ~78.5us @ 85-87% of write peak) we cannot control; our
// portion ~58us vs ~33us floor (E=134MB mandatory read).
constexpr int CN  = 2048;
constexpr int CK  = 8;
constexpr int CFN = 16;
constexpr int CO  = 32;

constexpr int JTILE  = 256;
constexpr int NJT    = CN / JTILE;     // 8
constexpr int CHUNK  = 16;
constexpr int NCHUNK = CN / CHUNK;     // 128 -> main grid 8x128 = 1024 blocks
constexpr int NACC   = CK + 1;         // 8 agg planes + 1 colsum plane

typedef float fx4 __attribute__((ext_vector_type(4)));  // native vec for nontemporal builtin

// Kernel 1: rinv[i] = 1/sum_j adj[i,j] (0 if non-finite)
__global__ __launch_bounds__(256) void rowsum_k(const float* __restrict__ adj,
                                                float* __restrict__ rinv) {
    const int i = blockIdx.x;
    const int t = threadIdx.x;
    const float4* row = (const float4*)(adj + (size_t)i * CN);  // 512 float4
    float4 v0 = row[t], v1 = row[t + 256];
    float s = v0.x + v0.y + v0.z + v0.w + v1.x + v1.y + v1.z + v1.w;
    #pragma unroll
    for (int off = 32; off > 0; off >>= 1) s += __shfl_down(s, off, 64);
    __shared__ float partial[4];
    if ((t & 63) == 0) partial[t >> 6] = s;
    __syncthreads();
    if (t == 0) {
        float tot = partial[0] + partial[1] + partial[2] + partial[3];
        float r = 1.0f / tot;
        if (!isfinite(r)) r = 0.0f;
        rinv[i] = r;
    }
}

// Kernel 2: stream E; per-thread j-column accumulators over a 16-row i-chunk;
// store partials to plane-major layout part[k][ic][j] (coalesced, no atomics).
__global__ __launch_bounds__(256, 4) void main_k(const float* __restrict__ E,
                                                 const float* __restrict__ adj,
                                                 const float* __restrict__ rinv,
                                                 float* __restrict__ part) {
    const int t  = threadIdx.x;
    const int j  = blockIdx.x * JTILE + t;
    const int ic = blockIdx.y;
    const int i0 = ic * CHUNK;

    float acc[NACC];
    #pragma unroll
    for (int k = 0; k < NACC; ++k) acc[k] = 0.f;

    #pragma unroll 8
    for (int ii = 0; ii < CHUNK; ++ii) {
        const int i = i0 + ii;
        const float a = rinv[i] * adj[(size_t)i * CN + j];
        const fx4* ev = (const fx4*)(E + ((size_t)i * CN + j) * CK); // 32B/lane
        const fx4 e0 = __builtin_nontemporal_load(ev);      // E streamed once:
        const fx4 e1 = __builtin_nontemporal_load(ev + 1);  // don't pollute L2/L3
        acc[0] += a * e0.x; acc[1] += a * e0.y;
        acc[2] += a * e0.z; acc[3] += a * e0.w;
        acc[4] += a * e1.x; acc[5] += a * e1.y;
        acc[6] += a * e1.z; acc[7] += a * e1.w;
        acc[8] += a;
    }

    #pragma unroll
    for (int k = 0; k < NACC; ++k)
        part[(size_t)k * (NCHUNK * CN) + (size_t)ic * CN + j] = acc[k];
}

// Kernel 3 (fused reduce + epilogue): each block owns 64 j-columns.
// Phase 1: 4 thread-groups x 64 lanes sum 32 ic-chunks each per plane
// (coalesced 256B/wave loads of part). Phase 2: LDS tree-finish ->
// agg[k][jl]. Phase 3: out[j,o] = sum_k agg*W + colsum*NF@Wn.
__global__ __launch_bounds__(256) void tail_k(const float* __restrict__ part,
                                              const float* __restrict__ nf,
                                              const float* __restrict__ wt,
                                              float* __restrict__ out) {
    __shared__ float pgrp[4][NACC][64];           // 9 KB
    __shared__ float agg[NACC][64];               // 2.25 KB
    __shared__ float wlds[(CK + CFN) * CO];       // 3 KB
    const int t  = threadIdx.x;
    const int j0 = blockIdx.x * 64;
    const int jl = t & 63;
    const int g  = t >> 6;                        // 4 groups

    #pragma unroll
    for (int idx = t; idx < (CK + CFN) * CO; idx += 256) wlds[idx] = wt[idx];

    #pragma unroll
    for (int k = 0; k < NACC; ++k) {
        const float* p = part + (size_t)k * (NCHUNK * CN) + j0 + jl
                              + (size_t)g * (NCHUNK / 4) * CN;
        float s = 0.f;
        #pragma unroll 8
        for (int m = 0; m < NCHUNK / 4; ++m)      // 32 ic per group
            s += p[(size_t)m * CN];
        pgrp[g][k][jl] = s;
    }
    __syncthreads();

    for (int idx = t; idx < NACC * 64; idx += 256) {
        const int k = idx >> 6, j = idx & 63;
        agg[k][j] = pgrp[0][k][j] + pgrp[1][k][j] + pgrp[2][k][j] + pgrp[3][k][j];
    }
    __syncthreads();

    const int o    = t & 31;
    const int jsub = t >> 5;                      // 0..7
    #pragma unroll
    for (int it = 0; it < 8; ++it) {
        const int jl2 = jsub * 8 + it;            // 0..63
        const int j   = j0 + jl2;
        float s1 = 0.f;
        #pragma unroll
        for (int k = 0; k < CK; ++k)
            s1 += agg[k][jl2] * wlds[k * CO + o];
        float s2 = 0.f;
        #pragma unroll
        for (int f = 0; f < CFN; ++f)
            s2 += nf[(size_t)j * CFN + f] * wlds[(CK + f) * CO + o];
        out[(size_t)j * CO + o] = s1 + agg[CK][jl2] * s2;
    }
}

extern "C" void kernel_launch(void* const* d_in, const int* in_sizes, int n_in,
                              void* d_out, int out_size, void* d_ws, size_t ws_size,
                              hipStream_t stream) {
    // Bind inputs BY ELEMENT COUNT (all four counts distinct).
    const float *nf = nullptr, *E = nullptr, *adj = nullptr, *wt = nullptr;
    for (int i = 0; i < n_in; ++i) {
        switch (in_sizes[i]) {
            case CN * CFN:        nf  = (const float*)d_in[i]; break;  // 32768
            case CN * CN * CK:    E   = (const float*)d_in[i]; break;  // 33554432
            case CN * CN:         adj = (const float*)d_in[i]; break;  // 4194304
            case (CK + CFN) * CO: wt  = (const float*)d_in[i]; break;  // 768
        }
    }
    float* out = (float*)d_out;

    // ws (fp32): rinv[2048] | part[9*128*2048]  (~9.5 MB used)
    // Every ws word consumed is written first by a prior kernel -> no memset.
    float* rinv = (float*)d_ws;
    float* part = rinv + CN;

    rowsum_k<<<CN, 256, 0, stream>>>(adj, rinv);
    main_k<<<dim3(NJT, NCHUNK), 256, 0, stream>>>(E, adj, rinv, part);
    tail_k<<<CN / 64, 256, 0, stream>>>(part, nf, wt, out);
}

// Round 4
// 214.345 us; speedup vs baseline: 1.0861x; 1.0861x over previous
//
#include <hip/hip_runtime.h>
#include <hip/hip_bf16.h>

// GraphNodeEdgeConvolution: N=2048, K=8, FN=16, O=32
// fp32 in / fp32 out. Inputs bound BY SIZE.
// R9 = revert to R7 (best verified: 214.6us). R8's reduce+epilogue fusion
// regressed +18us: tail_k had only 32 blocks (1/8 of machine) doing the
// 9.4MB part reduction with 256B/wave strided reads. Lesson: never trade
// grid-wide parallelism for a ~2us launch saving on a 256-CU chip.
// Accounting (R0-R8 evidence): ~157us/iter is harness workspace poison
// fill (2x 512MiB @ 85-87% of write peak, unoptimizable); our ~58us vs
// ~35us floor; occupancy/unroll/NT/fusion levers all neutral or worse.
constexpr int CN  = 2048;
constexpr int CK  = 8;
constexpr int CFN = 16;
constexpr int CO  = 32;

constexpr int JTILE  = 256;
constexpr int NJT    = CN / JTILE;     // 8
constexpr int CHUNK  = 16;
constexpr int NCHUNK = CN / CHUNK;     // 128 -> main grid 8x128 = 1024 blocks
constexpr int NACC   = CK + 1;         // 8 agg planes + 1 colsum plane

typedef float fx4 __attribute__((ext_vector_type(4)));  // native vec for nontemporal builtin

// Kernel 1: rinv[i] = 1/sum_j adj[i,j] (0 if non-finite)
__global__ __launch_bounds__(256) void rowsum_k(const float* __restrict__ adj,
                                                float* __restrict__ rinv) {
    const int i = blockIdx.x;
    const int t = threadIdx.x;
    const float4* row = (const float4*)(adj + (size_t)i * CN);  // 512 float4
    float4 v0 = row[t], v1 = row[t + 256];
    float s = v0.x + v0.y + v0.z + v0.w + v1.x + v1.y + v1.z + v1.w;
    #pragma unroll
    for (int off = 32; off > 0; off >>= 1) s += __shfl_down(s, off, 64);
    __shared__ float partial[4];
    if ((t & 63) == 0) partial[t >> 6] = s;
    __syncthreads();
    if (t == 0) {
        float tot = partial[0] + partial[1] + partial[2] + partial[3];
        float r = 1.0f / tot;
        if (!isfinite(r)) r = 0.0f;
        rinv[i] = r;
    }
}

// Kernel 2: stream E; per-thread j-column accumulators over a 16-row i-chunk;
// store partials to plane-major layout part[k][ic][j] (coalesced, no atomics).
// 1024 blocks, 4 blocks/CU. BW-bound (proven R7: occupancy bump neutral).
__global__ __launch_bounds__(256, 4) void main_k(const float* __restrict__ E,
                                                 const float* __restrict__ adj,
                                                 const float* __restrict__ rinv,
                                                 float* __restrict__ part) {
    const int t  = threadIdx.x;
    const int j  = blockIdx.x * JTILE + t;
    const int ic = blockIdx.y;
    const int i0 = ic * CHUNK;

    float acc[NACC];
    #pragma unroll
    for (int k = 0; k < NACC; ++k) acc[k] = 0.f;

    #pragma unroll 8
    for (int ii = 0; ii < CHUNK; ++ii) {
        const int i = i0 + ii;
        const float a = rinv[i] * adj[(size_t)i * CN + j];
        const fx4* ev = (const fx4*)(E + ((size_t)i * CN + j) * CK); // 32B/lane
        const fx4 e0 = __builtin_nontemporal_load(ev);      // E streamed once:
        const fx4 e1 = __builtin_nontemporal_load(ev + 1);  // don't pollute L2/L3
        acc[0] += a * e0.x; acc[1] += a * e0.y;
        acc[2] += a * e0.z; acc[3] += a * e0.w;
        acc[4] += a * e1.x; acc[5] += a * e1.y;
        acc[6] += a * e1.z; acc[7] += a * e1.w;
        acc[8] += a;
    }

    #pragma unroll
    for (int k = 0; k < NACC; ++k)
        part[(size_t)k * (NCHUNK * CN) + (size_t)ic * CN + j] = acc[k];
}

// Kernel 3: reduce 128 chunks -> aggT[k][j] (k=8 plane is colsum)
__global__ __launch_bounds__(256) void reduce_k(const float* __restrict__ part,
                                                float* __restrict__ aggT) {
    const int gid = blockIdx.x * 256 + threadIdx.x;   // 0 .. 9*2048-1
    const int k = gid >> 11;         // gid / 2048
    const int j = gid & (CN - 1);
    const float* p = part + (size_t)k * (NCHUNK * CN) + j;
    float s = 0.f;
    #pragma unroll 8
    for (int ic = 0; ic < NCHUNK; ++ic) s += p[(size_t)ic * CN];
    aggT[gid] = s;
}

// Kernel 4: out[j,o] = sum_k aggT[k][j]*W[k,o] + col[j]*sum_f NF[j,f]*W[8+f,o]
__global__ __launch_bounds__(256) void epilogue_k(const float* __restrict__ aggT,
                                                  const float* __restrict__ nf,
                                                  const float* __restrict__ wt,
                                                  float* __restrict__ out) {
    const int gid = blockIdx.x * 256 + threadIdx.x;   // 0 .. N*O-1
    const int j = gid >> 5;
    const int o = gid & 31;
    float s1 = 0.f;
    #pragma unroll
    for (int k = 0; k < CK; ++k)
        s1 += aggT[(size_t)k * CN + j] * wt[k * CO + o];
    float s2 = 0.f;
    #pragma unroll
    for (int f = 0; f < CFN; ++f)
        s2 += nf[(size_t)j * CFN + f] * wt[(CK + f) * CO + o];
    out[gid] = s1 + aggT[(size_t)CK * CN + j] * s2;   // fp32 output
}

extern "C" void kernel_launch(void* const* d_in, const int* in_sizes, int n_in,
                              void* d_out, int out_size, void* d_ws, size_t ws_size,
                              hipStream_t stream) {
    // Bind inputs BY ELEMENT COUNT (all four counts distinct).
    const float *nf = nullptr, *E = nullptr, *adj = nullptr, *wt = nullptr;
    for (int i = 0; i < n_in; ++i) {
        switch (in_sizes[i]) {
            case CN * CFN:        nf  = (const float*)d_in[i]; break;  // 32768
            case CN * CN * CK:    E   = (const float*)d_in[i]; break;  // 33554432
            case CN * CN:         adj = (const float*)d_in[i]; break;  // 4194304
            case (CK + CFN) * CO: wt  = (const float*)d_in[i]; break;  // 768
        }
    }
    float* out = (float*)d_out;

    // ws (fp32): rinv[2048] | part[9*128*2048] | aggT[9*2048]  (~9.5 MB used)
    // Every ws word consumed is written first by a prior kernel -> no memset.
    float* rinv = (float*)d_ws;
    float* part = rinv + CN;
    float* aggT = part + (size_t)NACC * NCHUNK * CN;

    rowsum_k<<<CN, 256, 0, stream>>>(adj, rinv);
    main_k<<<dim3(NJT, NCHUNK), 256, 0, stream>>>(E, adj, rinv, part);
    reduce_k<<<(NACC * CN) / 256, 256, 0, stream>>>(part, aggT);
    epilogue_k<<<(CN * CO) / 256, 256, 0, stream>>>(aggT, nf, wt, out);
}